// Round 3
// baseline (1162.276 us; speedup 1.0000x reference)
//
#include <hip/hip_runtime.h>
#include <hip/hip_bf16.h>

typedef unsigned short u16;
typedef __bf16 bf16x8 __attribute__((ext_vector_type(8)));
typedef float f32x4 __attribute__((ext_vector_type(4)));

__device__ inline u16 f2b(float f) {
    __hip_bfloat16 h = __float2bfloat16(f);
    return *(u16*)&h;
}

#define BM 128
#define BN 128
#define BK 32
#define LDSS 40  // 32 + 8 pad shorts per row

// C[M,N] = A[M,K] * W[N,K]^T.  W is bf16 (pre-converted), row-major K-contiguous.
// A: AF32=1 -> float32 (converted to bf16 during LDS staging), AF32=0 -> bf16.
// EPI: 0 = store f32, 1 = silu -> bf16
template<int AF32, int EPI>
__global__ __launch_bounds__(256) void gemm_bt(const void* __restrict__ Av,
                                               const u16* __restrict__ W,
                                               void* __restrict__ Cv,
                                               int M, int N, int K) {
    __shared__ u16 lds_a[BM * LDSS];
    __shared__ u16 lds_b[BN * LDSS];
    const int tid  = threadIdx.x;
    const int wave = tid >> 6;
    const int lane = tid & 63;
    const int wr = wave >> 1, wc = wave & 1;   // 2x2 wave grid, 64x64 each
    const int quad = lane >> 4, l15 = lane & 15;
    const int bm = blockIdx.x * BM;
    const int bn = blockIdx.y * BN;

    f32x4 acc[4][4] = {};

    const int lrow = tid >> 2;    // 0..63
    const int lch  = tid & 3;     // 16B chunk within 32-k bf16 row

    for (int k0 = 0; k0 < K; k0 += BK) {
        __syncthreads();
        if (AF32) {
            const float* Af = (const float*)Av;
            const int srow = tid >> 3;   // 0..31
            const int sch  = tid & 7;    // float4 chunk within 32-k f32 row
            #pragma unroll
            for (int p = 0; p < 4; ++p) {
                const int r = p * 32 + srow;
                float4 va = *(const float4*)&Af[(size_t)(bm + r) * K + k0 + sch * 4];
                ushort4 pk = make_ushort4(f2b(va.x), f2b(va.y), f2b(va.z), f2b(va.w));
                *(ushort4*)&lds_a[r * LDSS + sch * 4] = pk;
            }
        } else {
            const u16* Ab = (const u16*)Av;
            *(uint4*)&lds_a[lrow * LDSS + lch * 8] =
                *(const uint4*)&Ab[(size_t)(bm + lrow) * K + k0 + lch * 8];
            *(uint4*)&lds_a[(lrow + 64) * LDSS + lch * 8] =
                *(const uint4*)&Ab[(size_t)(bm + lrow + 64) * K + k0 + lch * 8];
        }
        *(uint4*)&lds_b[lrow * LDSS + lch * 8] =
            *(const uint4*)&W[(size_t)(bn + lrow) * K + k0 + lch * 8];
        *(uint4*)&lds_b[(lrow + 64) * LDSS + lch * 8] =
            *(const uint4*)&W[(size_t)(bn + lrow + 64) * K + k0 + lch * 8];
        __syncthreads();

        bf16x8 af[4], bf[4];
        #pragma unroll
        for (int i = 0; i < 4; i++)
            af[i] = *(const bf16x8*)&lds_a[(wr * 64 + i * 16 + l15) * LDSS + quad * 8];
        #pragma unroll
        for (int j = 0; j < 4; j++)
            bf[j] = *(const bf16x8*)&lds_b[(wc * 64 + j * 16 + l15) * LDSS + quad * 8];
        #pragma unroll
        for (int i = 0; i < 4; i++)
            #pragma unroll
            for (int j = 0; j < 4; j++)
                acc[i][j] = __builtin_amdgcn_mfma_f32_16x16x32_bf16(af[i], bf[j], acc[i][j], 0, 0, 0);
    }

    #pragma unroll
    for (int i = 0; i < 4; i++) {
        #pragma unroll
        for (int j = 0; j < 4; j++) {
            #pragma unroll
            for (int r = 0; r < 4; r++) {
                const int row = bm + wr * 64 + i * 16 + quad * 4 + r;
                const int col = bn + wc * 64 + j * 16 + l15;
                float v = acc[i][j][r];
                if (EPI == 1) {
                    v = v / (1.f + __expf(-v));   // silu
                    ((__hip_bfloat16*)Cv)[(size_t)row * N + col] = __float2bfloat16(v);
                } else {
                    ((float*)Cv)[(size_t)row * N + col] = v;
                }
            }
        }
    }
}

// Convert all weights f32 -> bf16: W_in [1024x1024], concat(W_k,W_v,W_q,W_a) [256x1024], W_out [1024x64]
__global__ __launch_bounds__(256) void convert_w(const float* __restrict__ Win,
                                                 const float* __restrict__ Wk,
                                                 const float* __restrict__ Wv,
                                                 const float* __restrict__ Wq,
                                                 const float* __restrict__ Wa,
                                                 const float* __restrict__ Wout,
                                                 u16* __restrict__ Win16,
                                                 u16* __restrict__ Wc16,
                                                 u16* __restrict__ Wout16) {
    int idx = blockIdx.x * 256 + threadIdx.x;   // 0 .. 1376255
    if (idx < 1048576) { Win16[idx] = f2b(Win[idx]); return; }
    int i2 = idx - 1048576;
    if (i2 < 262144) {
        int which = i2 >> 16;
        int off = i2 & 65535;
        const float* s = (which == 0) ? Wk : (which == 1) ? Wv : (which == 2) ? Wq : Wa;
        Wc16[i2] = f2b(s[off]);
        return;
    }
    int i3 = i2 - 262144;
    Wout16[i3] = f2b(Wout[i3]);
}

#define T_LEN 2048
#define NS 64
#define PFD 16     // DMA prefetch distance (steps)
#define SLOTS 32   // LDS ring slots (2x distance: no WAR hazard on slot reuse)

// DPP-based xor-add within a 16-lane row (pure VALU, no DS pipe).
// CTRL: 0xB1 = quad_perm xor1, 0x4E = quad_perm xor2, 0x128 = row_ror:8 (= xor8 within row)
template<int CTRL>
__device__ inline float dpp_add(float x) {
    return x + __int_as_float(__builtin_amdgcn_mov_dpp(__float_as_int(x), CTRL, 0xf, 0xf, true));
}
__device__ inline float reduce8(float x) {
    // sum over the 8-lane group spanned by lane bits {0,1,3}
    x = dpp_add<0xB1>(x);    // xor 1
    x = dpp_add<0x4E>(x);    // xor 2
    x = dpp_add<0x128>(x);   // xor 8
    return x;
}

// Barrier-free scan. Grid: 128 blocks (16 batches x 8 row-groups), 64 threads (1 wave).
// XCD swizzle: b = blk & 15 -> all 8 row-group blocks of a batch share an XCD-L2.
// Lane layout: c (col chunk 0..7) = lane bits {0,1,3}, r (row 0..7) = bits {2,4,5};
// cross-chunk sums are xor1/xor2/xor8 = pure-DPP (VALU), no DS pipe in the chain.
//
// Prefetch: global_load_lds DMA ring (round-2 lesson: a VGPR ring gets dismantled
// by the scheduler's pressure heuristic; in-flight DMAs consume no VGPRs and the
// prefetch distance is pinned by explicit counted s_waitcnt vmcnt(N)).
// One P row = 256 f32 = 1KB = 64 lanes x 16B = exactly one width-16 DMA
// (wave-uniform LDS base + lane*16 linear dest; global src = row + lane*16).
// Per step t: issue DMA(t+PFD) -> s_waitcnt vmcnt(30) -> ds_read row t+1 into the
// other reg set -> compute row t.  vmcnt(30) derivation: asm memory-clobber fences
// pin region order, so between DMA(t+1) and step-t's wait sit exactly 15 DMAs +
// 15 cell stores (+<=1 same-region store); in-order vmcnt retirement => counter<=30
// implies DMA(t+1) landed. Prologue drains vmcnt(0) (covers t<PFD-1); tail drains
// once and runs un-pipelined (16 steps, ~1us exposed).
__global__ __launch_bounds__(64) void scan_kernel(const float* __restrict__ P,
                                                  const float* __restrict__ d_alpha,
                                                  const float* __restrict__ b_alpha,
                                                  __hip_bfloat16* __restrict__ cell,
                                                  float* __restrict__ Sout) {
    __shared__ float ldsbuf[SLOTS * 256];   // 32 KB ring

    const int blk = blockIdx.x;
    const int b = blk & 15;         // batch: same-b blocks share XCD (blk%8 const)
    const int w = blk >> 4;         // row-group 0..7
    const int lane = threadIdx.x;
    const int c = (lane & 3) | ((lane >> 1) & 4);        // col chunk (lane bits 0,1,3)
    const int r = ((lane >> 2) & 1) | ((lane >> 3) & 6); // row-in-group (bits 2,4,5)
    const int i = w * 8 + r;        // state row 0..63
    const int kc = c * 8;           // col base

    const float da = d_alpha[i];
    const float ba = b_alpha[i];
    const float* Pb = P + (size_t)b * T_LEN * 256;

    float s[8];
    #pragma unroll
    for (int j = 0; j < 8; j++) s[j] = 0.f;

    // two register sets (1-step lookahead out of LDS)
    float4 kaA, kbA, qaA, qbA; float vvA, aaA;
    float4 kaB, kbB, qaB, qbB; float vvB, aaB;

#define DMA(tn) __builtin_amdgcn_global_load_lds( \
        (const __attribute__((address_space(1))) void*)(Pb + (size_t)(tn) * 256 + lane * 4), \
        (__attribute__((address_space(3))) void*)(&ldsbuf[((tn) & (SLOTS - 1)) * 256]), \
        16, 0, 0)

#define READ(tn, X) do {                                        \
        const float* rp_ = &ldsbuf[((tn) & (SLOTS - 1)) * 256]; \
        ka##X = *(const float4*)&rp_[kc];                       \
        kb##X = *(const float4*)&rp_[kc + 4];                   \
        qa##X = *(const float4*)&rp_[128 + kc];                 \
        qb##X = *(const float4*)&rp_[128 + kc + 4];             \
        vv##X = rp_[64 + i];                                    \
        aa##X = rp_[192 + i];                                   \
    } while (0)

#define COMPUTE(t, X) do {                                                   \
        float rpa_ = s[0]*ka##X.x + s[1]*ka##X.y + s[2]*ka##X.z + s[3]*ka##X.w; \
        float rpb_ = s[4]*kb##X.x + s[5]*kb##X.y + s[6]*kb##X.z + s[7]*kb##X.w; \
        float rp_ = reduce8(rpa_ + rpb_);                                    \
        const float alpha_ = 1.f / (1.f + __expf(-(aa##X + da * rp_ + ba))); \
        const float cvk_ = (1.f - alpha_) * vv##X;                           \
        s[0] = alpha_ * s[0] + cvk_ * ka##X.x;                               \
        s[1] = alpha_ * s[1] + cvk_ * ka##X.y;                               \
        s[2] = alpha_ * s[2] + cvk_ * ka##X.z;                               \
        s[3] = alpha_ * s[3] + cvk_ * ka##X.w;                               \
        s[4] = alpha_ * s[4] + cvk_ * kb##X.x;                               \
        s[5] = alpha_ * s[5] + cvk_ * kb##X.y;                               \
        s[6] = alpha_ * s[6] + cvk_ * kb##X.z;                               \
        s[7] = alpha_ * s[7] + cvk_ * kb##X.w;                               \
        float opa_ = s[0]*qa##X.x + s[1]*qa##X.y + s[2]*qa##X.z + s[3]*qa##X.w; \
        float opb_ = s[4]*qb##X.x + s[5]*qb##X.y + s[6]*qb##X.z + s[7]*qb##X.w; \
        float op_ = reduce8(opa_ + opb_);                                    \
        const float sig_ = 1.f / (1.f + __expf(-op_));                       \
        const float o_ = op_ * op_ * sig_;                                   \
        if (c == 0)                                                          \
            cell[(size_t)(b * T_LEN + (t)) * NS + i] = __float2bfloat16(o_); \
    } while (0)

#define STEP(t, C, N) do {                                \
        DMA((t) + PFD);                                   \
        asm volatile("s_waitcnt vmcnt(30)" ::: "memory"); \
        READ((t) + 1, N);                                 \
        COMPUTE(t, C);                                    \
    } while (0)

    // prologue: fill first PFD rows, drain, read row 0
    #pragma unroll
    for (int p = 0; p < PFD; ++p) DMA(p);
    asm volatile("s_waitcnt vmcnt(0)" ::: "memory");
    READ(0, A);

    // main loop: steps 0 .. T_LEN-PFD-1, issuing DMAs up to row T_LEN-1
    for (int t = 0; t < T_LEN - PFD; t += 2) {
        STEP(t,     A, B);
        STEP(t + 1, B, A);
    }

    // tail: last PFD steps, all rows resident after drain; no pipelining needed
    asm volatile("s_waitcnt vmcnt(0)" ::: "memory");
    for (int t = T_LEN - PFD; t < T_LEN - 1; ++t) {
        COMPUTE(t, A);
        READ(t + 1, A);
    }
    COMPUTE(T_LEN - 1, A);

#undef STEP
#undef COMPUTE
#undef READ
#undef DMA

    // final state
    float4 s0 = make_float4(s[0], s[1], s[2], s[3]);
    float4 s1 = make_float4(s[4], s[5], s[6], s[7]);
    *(float4*)&Sout[(size_t)b * 4096 + i * 64 + kc]     = s0;
    *(float4*)&Sout[(size_t)b * 4096 + i * 64 + kc + 4] = s1;
}

extern "C" void kernel_launch(void* const* d_in, const int* in_sizes, int n_in,
                              void* d_out, int out_size, void* d_ws, size_t ws_size,
                              hipStream_t stream) {
    const float* x     = (const float*)d_in[0];   // [32768, 1024] f32
    const float* W_in  = (const float*)d_in[1];   // [1024, 1024]
    const float* W_k   = (const float*)d_in[2];   // [64, 1024]
    const float* W_v   = (const float*)d_in[3];
    const float* W_q   = (const float*)d_in[4];
    const float* W_a   = (const float*)d_in[5];
    const float* d_alpha = (const float*)d_in[6]; // [64]
    const float* b_alpha = (const float*)d_in[7]; // [64]
    const float* W_out = (const float*)d_in[8];   // [1024, 64]

    char* ws = (char*)d_ws;
    u16*   xp     = (u16*)ws;                               // [0, 64MB)  bf16 32768x1024
    float* P      = (float*)(ws + (size_t)67108864);        // [64MB, 96MB) f32 32768x256
    u16*   Win16  = (u16*)(ws + (size_t)100663296);         // 2MB
    u16*   Wc16   = (u16*)(ws + (size_t)102760448);         // 512KB
    u16*   Wout16 = (u16*)(ws + (size_t)103284736);         // 128KB
    __hip_bfloat16* cell = (__hip_bfloat16*)ws;             // overlay [0,4MB): xp dead after P-proj

    float* out  = (float*)d_out;                  // [32768,1024] f32
    float* Sout = out + (size_t)32768 * 1024;     // [16,64,64] f32

    convert_w<<<dim3(5376), dim3(256), 0, stream>>>(W_in, W_k, W_v, W_q, W_a, W_out,
                                                    Win16, Wc16, Wout16);
    // xp = silu(x @ W_in^T), bf16
    gemm_bt<1, 1><<<dim3(256, 8), dim3(256), 0, stream>>>((const void*)x, Win16, (void*)xp,
                                                          32768, 1024, 1024);
    // P = xp @ Wc^T  (k|v|q|ax), f32
    gemm_bt<0, 0><<<dim3(256, 2), dim3(256), 0, stream>>>((const void*)xp, Wc16, (void*)P,
                                                          32768, 256, 1024);
    // barrier-free sequential gated scan -> cell (bf16), Sout (f32)
    scan_kernel<<<dim3(128), dim3(64), 0, stream>>>(P, d_alpha, b_alpha, cell, Sout);
    // out = cell @ W_out^T, f32
    gemm_bt<0, 0><<<dim3(256, 8), dim3(256), 0, stream>>>((const void*)cell, Wout16, (void*)out,
                                                          32768, 1024, 64);
}

// Round 4
// 918.063 us; speedup vs baseline: 1.2660x; 1.2660x over previous
//
#include <hip/hip_runtime.h>
#include <hip/hip_bf16.h>

typedef unsigned short u16;
typedef __bf16 bf16x8 __attribute__((ext_vector_type(8)));
typedef float f32x4 __attribute__((ext_vector_type(4)));

__device__ inline u16 f2b(float f) {
    __hip_bfloat16 h = __float2bfloat16(f);
    return *(u16*)&h;
}

#define BM 128
#define BN 128
#define BK 32
#define LDSS 40  // 32 + 8 pad shorts per row

// C[M,N] = A[M,K] * W[N,K]^T.  W is bf16 (pre-converted), row-major K-contiguous.
// A: AF32=1 -> float32 (converted to bf16 during LDS staging), AF32=0 -> bf16.
// EPI: 0 = store f32, 1 = silu -> bf16
template<int AF32, int EPI>
__global__ __launch_bounds__(256) void gemm_bt(const void* __restrict__ Av,
                                               const u16* __restrict__ W,
                                               void* __restrict__ Cv,
                                               int M, int N, int K) {
    __shared__ u16 lds_a[BM * LDSS];
    __shared__ u16 lds_b[BN * LDSS];
    const int tid  = threadIdx.x;
    const int wave = tid >> 6;
    const int lane = tid & 63;
    const int wr = wave >> 1, wc = wave & 1;   // 2x2 wave grid, 64x64 each
    const int quad = lane >> 4, l15 = lane & 15;
    const int bm = blockIdx.x * BM;
    const int bn = blockIdx.y * BN;

    f32x4 acc[4][4] = {};

    const int lrow = tid >> 2;    // 0..63
    const int lch  = tid & 3;     // 16B chunk within 32-k bf16 row

    for (int k0 = 0; k0 < K; k0 += BK) {
        __syncthreads();
        if (AF32) {
            const float* Af = (const float*)Av;
            const int srow = tid >> 3;   // 0..31
            const int sch  = tid & 7;    // float4 chunk within 32-k f32 row
            #pragma unroll
            for (int p = 0; p < 4; ++p) {
                const int r = p * 32 + srow;
                float4 va = *(const float4*)&Af[(size_t)(bm + r) * K + k0 + sch * 4];
                ushort4 pk = make_ushort4(f2b(va.x), f2b(va.y), f2b(va.z), f2b(va.w));
                *(ushort4*)&lds_a[r * LDSS + sch * 4] = pk;
            }
        } else {
            const u16* Ab = (const u16*)Av;
            *(uint4*)&lds_a[lrow * LDSS + lch * 8] =
                *(const uint4*)&Ab[(size_t)(bm + lrow) * K + k0 + lch * 8];
            *(uint4*)&lds_a[(lrow + 64) * LDSS + lch * 8] =
                *(const uint4*)&Ab[(size_t)(bm + lrow + 64) * K + k0 + lch * 8];
        }
        *(uint4*)&lds_b[lrow * LDSS + lch * 8] =
            *(const uint4*)&W[(size_t)(bn + lrow) * K + k0 + lch * 8];
        *(uint4*)&lds_b[(lrow + 64) * LDSS + lch * 8] =
            *(const uint4*)&W[(size_t)(bn + lrow + 64) * K + k0 + lch * 8];
        __syncthreads();

        bf16x8 af[4], bf[4];
        #pragma unroll
        for (int i = 0; i < 4; i++)
            af[i] = *(const bf16x8*)&lds_a[(wr * 64 + i * 16 + l15) * LDSS + quad * 8];
        #pragma unroll
        for (int j = 0; j < 4; j++)
            bf[j] = *(const bf16x8*)&lds_b[(wc * 64 + j * 16 + l15) * LDSS + quad * 8];
        #pragma unroll
        for (int i = 0; i < 4; i++)
            #pragma unroll
            for (int j = 0; j < 4; j++)
                acc[i][j] = __builtin_amdgcn_mfma_f32_16x16x32_bf16(af[i], bf[j], acc[i][j], 0, 0, 0);
    }

    #pragma unroll
    for (int i = 0; i < 4; i++) {
        #pragma unroll
        for (int j = 0; j < 4; j++) {
            #pragma unroll
            for (int r = 0; r < 4; r++) {
                const int row = bm + wr * 64 + i * 16 + quad * 4 + r;
                const int col = bn + wc * 64 + j * 16 + l15;
                float v = acc[i][j][r];
                if (EPI == 1) {
                    v = v / (1.f + __expf(-v));   // silu
                    ((__hip_bfloat16*)Cv)[(size_t)row * N + col] = __float2bfloat16(v);
                } else {
                    ((float*)Cv)[(size_t)row * N + col] = v;
                }
            }
        }
    }
}

// Convert all weights f32 -> bf16: W_in [1024x1024], concat(W_k,W_v,W_q,W_a) [256x1024], W_out [1024x64]
__global__ __launch_bounds__(256) void convert_w(const float* __restrict__ Win,
                                                 const float* __restrict__ Wk,
                                                 const float* __restrict__ Wv,
                                                 const float* __restrict__ Wq,
                                                 const float* __restrict__ Wa,
                                                 const float* __restrict__ Wout,
                                                 u16* __restrict__ Win16,
                                                 u16* __restrict__ Wc16,
                                                 u16* __restrict__ Wout16) {
    int idx = blockIdx.x * 256 + threadIdx.x;   // 0 .. 1376255
    if (idx < 1048576) { Win16[idx] = f2b(Win[idx]); return; }
    int i2 = idx - 1048576;
    if (i2 < 262144) {
        int which = i2 >> 16;
        int off = i2 & 65535;
        const float* s = (which == 0) ? Wk : (which == 1) ? Wv : (which == 2) ? Wq : Wa;
        Wc16[i2] = f2b(s[off]);
        return;
    }
    int i3 = i2 - 262144;
    Wout16[i3] = f2b(Wout[i3]);
}

#define T_LEN 2048
#define NS 64
#define PF 8   // prefetch ring depth (steps)

// DPP-based xor-add within a 16-lane row (pure VALU, no DS pipe).
// CTRL: 0xB1 = quad_perm xor1, 0x4E = quad_perm xor2, 0x128 = row_ror:8 (= xor8 within row)
template<int CTRL>
__device__ inline float dpp_add(float x) {
    return x + __int_as_float(__builtin_amdgcn_mov_dpp(__float_as_int(x), CTRL, 0xf, 0xf, true));
}
__device__ inline float reduce8(float x) {
    // sum over the 8-lane group spanned by lane bits {0,1,3}
    x = dpp_add<0xB1>(x);    // xor 1
    x = dpp_add<0x4E>(x);    // xor 2
    x = dpp_add<0x128>(x);   // xor 8
    return x;
}

// Barrier-free scan. Grid: 128 blocks (16 batches x 8 row-groups), 64 threads (1 wave).
// XCD swizzle: b = blk & 15 -> all 8 row-group blocks of a batch share an XCD-L2.
// Lane layout: c (col chunk 0..7) = lane bits {0,1,3}, r (row 0..7) = bits {2,4,5};
// cross-chunk sums are xor1/xor2/xor8 = pure-DPP (VALU), no DS pipe in the chain.
//
// Prefetch: PF=8 register ring with a PER-STEP COMPILER MEMORY FENCE
// (asm volatile "" ::: "memory") placed right after each step's prefetch loads.
// History: R1/R2 plain ring -> scheduler HEURISTICALLY sank loads to ~2-3 steps
// (VGPR capped ~120, ~400cyc exposed latency/step). R3 global_load_lds DMA ring
// -> regressed to 905cyc/step (suspected same-wave ds_read-behind-DMA hazard;
// reverted). The fence makes sinking ILLEGAL: a load cannot cross a memory
// clobber in either direction, so each slot's loads stay pinned 8 steps ahead
// of use and the ring (144 VGPRs) must stay resident. Unlike sched_barrier(0),
// only memory ops are pinned -- the off-chain o-path still overlaps.
// Verification signal: VGPR_Count ~190-230 (ring resident). Tail peeled.
__global__ __launch_bounds__(64, 1) void scan_kernel(const float* __restrict__ P,
                                                     const float* __restrict__ d_alpha,
                                                     const float* __restrict__ b_alpha,
                                                     __hip_bfloat16* __restrict__ cell,
                                                     float* __restrict__ Sout) {
    const int blk = blockIdx.x;
    const int b = blk & 15;         // batch: same-b blocks share XCD (blk%8 const)
    const int w = blk >> 4;         // row-group 0..7
    const int lane = threadIdx.x;
    const int c = (lane & 3) | ((lane >> 1) & 4);        // col chunk (lane bits 0,1,3)
    const int r = ((lane >> 2) & 1) | ((lane >> 3) & 6); // row-in-group (bits 2,4,5)
    const int i = w * 8 + r;        // state row 0..63
    const int kc = c * 8;           // col base

    const float da = d_alpha[i];
    const float ba = b_alpha[i];
    const float* Pb = P + (size_t)b * T_LEN * 256;

    float s[8];
    #pragma unroll
    for (int j = 0; j < 8; j++) s[j] = 0.f;

    // ring buffers: PF slots, register-resident (pinned by per-step fences)
    float4 ka[PF], kb[PF], qa[PF], qb[PF];
    float  vv[PF], aa[PF];

#define FENCE asm volatile("" ::: "memory")

#define PREFETCH(p, tn) do {                                   \
        const float* row_ = &Pb[(size_t)(tn) * 256];           \
        ka[p] = *(const float4*)&row_[kc];                     \
        kb[p] = *(const float4*)&row_[kc + 4];                 \
        qa[p] = *(const float4*)&row_[128 + kc];               \
        qb[p] = *(const float4*)&row_[128 + kc + 4];           \
        vv[p] = row_[64 + i];                                  \
        aa[p] = row_[192 + i];                                 \
    } while (0)

#define SCAN_STEP(p, t, PRE) do {                              \
        const float4 k0 = ka[p], k1 = kb[p];                   \
        const float4 q0 = qa[p], q1 = qb[p];                   \
        const float v = vv[p], ax = aa[p];                     \
        PRE;                                                   \
        FENCE;                                                 \
        float rpa = s[0]*k0.x + s[1]*k0.y + s[2]*k0.z + s[3]*k0.w; \
        float rpb = s[4]*k1.x + s[5]*k1.y + s[6]*k1.z + s[7]*k1.w; \
        float rp = reduce8(rpa + rpb);                         \
        const float alpha = 1.f / (1.f + __expf(-(ax + da * rp + ba))); \
        const float cvk = (1.f - alpha) * v;                   \
        s[0] = alpha * s[0] + cvk * k0.x;                      \
        s[1] = alpha * s[1] + cvk * k0.y;                      \
        s[2] = alpha * s[2] + cvk * k0.z;                      \
        s[3] = alpha * s[3] + cvk * k0.w;                      \
        s[4] = alpha * s[4] + cvk * k1.x;                      \
        s[5] = alpha * s[5] + cvk * k1.y;                      \
        s[6] = alpha * s[6] + cvk * k1.z;                      \
        s[7] = alpha * s[7] + cvk * k1.w;                      \
        float opa = s[0]*q0.x + s[1]*q0.y + s[2]*q0.z + s[3]*q0.w; \
        float opb = s[4]*q1.x + s[5]*q1.y + s[6]*q1.z + s[7]*q1.w; \
        float op = reduce8(opa + opb);                         \
        const float sig = 1.f / (1.f + __expf(-op));           \
        const float o = op * op * sig;                         \
        if (c == 0)                                            \
            cell[(size_t)(b * T_LEN + (t)) * NS + i] = __float2bfloat16(o); \
    } while (0)

    // prologue: fill all PF slots, fence once
    #pragma unroll
    for (int p = 0; p < PF; ++p) PREFETCH(p, p);
    FENCE;

    // main loop: unconditional prefetch (t+PF <= T_LEN-1 always holds here)
    for (int t0 = 0; t0 < T_LEN - PF; t0 += PF) {
        #pragma unroll
        for (int p = 0; p < PF; ++p) {
            const int t = t0 + p;
            SCAN_STEP(p, t, PREFETCH(p, t + PF));
        }
    }
    // peeled tail: last PF steps, no prefetch
    #pragma unroll
    for (int p = 0; p < PF; ++p) {
        const int t = T_LEN - PF + p;
        SCAN_STEP(p, t, (void)0);
    }

#undef SCAN_STEP
#undef PREFETCH
#undef FENCE

    // final state
    float4 s0 = make_float4(s[0], s[1], s[2], s[3]);
    float4 s1 = make_float4(s[4], s[5], s[6], s[7]);
    *(float4*)&Sout[(size_t)b * 4096 + i * 64 + kc]     = s0;
    *(float4*)&Sout[(size_t)b * 4096 + i * 64 + kc + 4] = s1;
}

extern "C" void kernel_launch(void* const* d_in, const int* in_sizes, int n_in,
                              void* d_out, int out_size, void* d_ws, size_t ws_size,
                              hipStream_t stream) {
    const float* x     = (const float*)d_in[0];   // [32768, 1024] f32
    const float* W_in  = (const float*)d_in[1];   // [1024, 1024]
    const float* W_k   = (const float*)d_in[2];   // [64, 1024]
    const float* W_v   = (const float*)d_in[3];
    const float* W_q   = (const float*)d_in[4];
    const float* W_a   = (const float*)d_in[5];
    const float* d_alpha = (const float*)d_in[6]; // [64]
    const float* b_alpha = (const float*)d_in[7]; // [64]
    const float* W_out = (const float*)d_in[8];   // [1024, 64]

    char* ws = (char*)d_ws;
    u16*   xp     = (u16*)ws;                               // [0, 64MB)  bf16 32768x1024
    float* P      = (float*)(ws + (size_t)67108864);        // [64MB, 96MB) f32 32768x256
    u16*   Win16  = (u16*)(ws + (size_t)100663296);         // 2MB
    u16*   Wc16   = (u16*)(ws + (size_t)102760448);         // 512KB
    u16*   Wout16 = (u16*)(ws + (size_t)103284736);         // 128KB
    __hip_bfloat16* cell = (__hip_bfloat16*)ws;             // overlay [0,4MB): xp dead after P-proj

    float* out  = (float*)d_out;                  // [32768,1024] f32
    float* Sout = out + (size_t)32768 * 1024;     // [16,64,64] f32

    convert_w<<<dim3(5376), dim3(256), 0, stream>>>(W_in, W_k, W_v, W_q, W_a, W_out,
                                                    Win16, Wc16, Wout16);
    // xp = silu(x @ W_in^T), bf16
    gemm_bt<1, 1><<<dim3(256, 8), dim3(256), 0, stream>>>((const void*)x, Win16, (void*)xp,
                                                          32768, 1024, 1024);
    // P = xp @ Wc^T  (k|v|q|ax), f32
    gemm_bt<0, 0><<<dim3(256, 2), dim3(256), 0, stream>>>((const void*)xp, Wc16, (void*)P,
                                                          32768, 256, 1024);
    // barrier-free sequential gated scan -> cell (bf16), Sout (f32)
    scan_kernel<<<dim3(128), dim3(64), 0, stream>>>(P, d_alpha, b_alpha, cell, Sout);
    // out = cell @ W_out^T, f32
    gemm_bt<0, 0><<<dim3(256, 8), dim3(256), 0, stream>>>((const void*)cell, Wout16, (void*)out,
                                                          32768, 1024, 64);
}

// Round 5
// 822.183 us; speedup vs baseline: 1.4136x; 1.1166x over previous
//
#include <hip/hip_runtime.h>
#include <hip/hip_bf16.h>

typedef unsigned short u16;
typedef __bf16 bf16x8 __attribute__((ext_vector_type(8)));
typedef float f32x4 __attribute__((ext_vector_type(4)));

__device__ inline u16 f2b(float f) {
    __hip_bfloat16 h = __float2bfloat16(f);
    return *(u16*)&h;
}

#define BM 128
#define BN 128
#define BK 32
#define LDSS 40  // 32 + 8 pad shorts per row

// C[M,N] = A[M,K] * W[N,K]^T.  W is bf16 (pre-converted), row-major K-contiguous.
// A: AF32=1 -> float32 (converted to bf16 during LDS staging), AF32=0 -> bf16.
// EPI: 0 = store f32, 1 = silu -> bf16
template<int AF32, int EPI>
__global__ __launch_bounds__(256) void gemm_bt(const void* __restrict__ Av,
                                               const u16* __restrict__ W,
                                               void* __restrict__ Cv,
                                               int M, int N, int K) {
    __shared__ u16 lds_a[BM * LDSS];
    __shared__ u16 lds_b[BN * LDSS];
    const int tid  = threadIdx.x;
    const int wave = tid >> 6;
    const int lane = tid & 63;
    const int wr = wave >> 1, wc = wave & 1;   // 2x2 wave grid, 64x64 each
    const int quad = lane >> 4, l15 = lane & 15;
    const int bm = blockIdx.x * BM;
    const int bn = blockIdx.y * BN;

    f32x4 acc[4][4] = {};

    const int lrow = tid >> 2;    // 0..63
    const int lch  = tid & 3;     // 16B chunk within 32-k bf16 row

    for (int k0 = 0; k0 < K; k0 += BK) {
        __syncthreads();
        if (AF32) {
            const float* Af = (const float*)Av;
            const int srow = tid >> 3;   // 0..31
            const int sch  = tid & 7;    // float4 chunk within 32-k f32 row
            #pragma unroll
            for (int p = 0; p < 4; ++p) {
                const int r = p * 32 + srow;
                float4 va = *(const float4*)&Af[(size_t)(bm + r) * K + k0 + sch * 4];
                ushort4 pk = make_ushort4(f2b(va.x), f2b(va.y), f2b(va.z), f2b(va.w));
                *(ushort4*)&lds_a[r * LDSS + sch * 4] = pk;
            }
        } else {
            const u16* Ab = (const u16*)Av;
            *(uint4*)&lds_a[lrow * LDSS + lch * 8] =
                *(const uint4*)&Ab[(size_t)(bm + lrow) * K + k0 + lch * 8];
            *(uint4*)&lds_a[(lrow + 64) * LDSS + lch * 8] =
                *(const uint4*)&Ab[(size_t)(bm + lrow + 64) * K + k0 + lch * 8];
        }
        *(uint4*)&lds_b[lrow * LDSS + lch * 8] =
            *(const uint4*)&W[(size_t)(bn + lrow) * K + k0 + lch * 8];
        *(uint4*)&lds_b[(lrow + 64) * LDSS + lch * 8] =
            *(const uint4*)&W[(size_t)(bn + lrow + 64) * K + k0 + lch * 8];
        __syncthreads();

        bf16x8 af[4], bf[4];
        #pragma unroll
        for (int i = 0; i < 4; i++)
            af[i] = *(const bf16x8*)&lds_a[(wr * 64 + i * 16 + l15) * LDSS + quad * 8];
        #pragma unroll
        for (int j = 0; j < 4; j++)
            bf[j] = *(const bf16x8*)&lds_b[(wc * 64 + j * 16 + l15) * LDSS + quad * 8];
        #pragma unroll
        for (int i = 0; i < 4; i++)
            #pragma unroll
            for (int j = 0; j < 4; j++)
                acc[i][j] = __builtin_amdgcn_mfma_f32_16x16x32_bf16(af[i], bf[j], acc[i][j], 0, 0, 0);
    }

    #pragma unroll
    for (int i = 0; i < 4; i++) {
        #pragma unroll
        for (int j = 0; j < 4; j++) {
            #pragma unroll
            for (int r = 0; r < 4; r++) {
                const int row = bm + wr * 64 + i * 16 + quad * 4 + r;
                const int col = bn + wc * 64 + j * 16 + l15;
                float v = acc[i][j][r];
                if (EPI == 1) {
                    v = v / (1.f + __expf(-v));   // silu
                    ((__hip_bfloat16*)Cv)[(size_t)row * N + col] = __float2bfloat16(v);
                } else {
                    ((float*)Cv)[(size_t)row * N + col] = v;
                }
            }
        }
    }
}

// Convert all weights f32 -> bf16: W_in [1024x1024], concat(W_k,W_v,W_q,W_a) [256x1024], W_out [1024x64]
__global__ __launch_bounds__(256) void convert_w(const float* __restrict__ Win,
                                                 const float* __restrict__ Wk,
                                                 const float* __restrict__ Wv,
                                                 const float* __restrict__ Wq,
                                                 const float* __restrict__ Wa,
                                                 const float* __restrict__ Wout,
                                                 u16* __restrict__ Win16,
                                                 u16* __restrict__ Wc16,
                                                 u16* __restrict__ Wout16) {
    int idx = blockIdx.x * 256 + threadIdx.x;   // 0 .. 1376255
    if (idx < 1048576) { Win16[idx] = f2b(Win[idx]); return; }
    int i2 = idx - 1048576;
    if (i2 < 262144) {
        int which = i2 >> 16;
        int off = i2 & 65535;
        const float* s = (which == 0) ? Wk : (which == 1) ? Wv : (which == 2) ? Wq : Wa;
        Wc16[i2] = f2b(s[off]);
        return;
    }
    int i3 = i2 - 262144;
    Wout16[i3] = f2b(Wout[i3]);
}

#define T_LEN 2048
#define NS 64
#define CHR 32            // P rows per LDS chunk
#define NCH (T_LEN / CHR) // 64 chunks

// DPP-based xor-add (pure VALU, no DS pipe).
// CTRL: 0xB1 = quad_perm xor1, 0x4E = quad_perm xor2, 0x128 = row_ror:8 (= xor8 within row)
template<int CTRL>
__device__ inline float dpp_add(float x) {
    return x + __int_as_float(__builtin_amdgcn_mov_dpp(__float_as_int(x), CTRL, 0xf, 0xf, true));
}
__device__ inline float reduce8(float x) {
    // sum over the 8-lane group spanned by lane bits {0,1,3}
    x = dpp_add<0xB1>(x);    // xor 1
    x = dpp_add<0x4E>(x);    // xor 2
    x = dpp_add<0x128>(x);   // xor 8
    return x;
}

// Producer-consumer scan. Grid: 128 blocks (16 batches x 8 row-groups),
// 128 threads = 2 waves: wave 1 streams P into a double-buffered LDS chunk ring
// (32 rows = 32KB per chunk); wave 0 runs the serial recurrence reading ONLY LDS.
//
// Rationale (R1-R4 post-mortems): the serial wave cannot be made to hold a deep
// global-load prefetch ring -- the allocator/scheduler collapses it to ~2-3 steps
// (VGPR pinned ~120 across plain ring / launch_bounds / memory-fence attempts),
// exposing ~400cyc of L2/L3 latency per step; the global_load_lds DMA ring (R3)
// regressed to 905cyc/step. Producer-consumer removes global loads from the
// serial wave entirely: LDS latency (~120cyc) < step time, so the compiler's
// natural 1-2 step ds_read lookahead suffices. One __syncthreads per 32 steps
// (double buffer flip; producer is a full chunk ahead and ~10% loaded, so the
// consumer's barrier wait ~= 0 + store drain).
// XCD swizzle: b = blk & 15 -> the 8 row-group blocks of a batch share an XCD L2.
// Lane layout: c (col chunk 0..7) = lane bits {0,1,3}, r (row 0..7) = bits {2,4,5};
// cross-chunk sums are xor1/xor2/xor8 = pure-DPP.
__global__ __launch_bounds__(128) void scan_kernel(const float* __restrict__ P,
                                                   const float* __restrict__ d_alpha,
                                                   const float* __restrict__ b_alpha,
                                                   __hip_bfloat16* __restrict__ cell,
                                                   float* __restrict__ Sout) {
    __shared__ float lbuf[2][CHR * 256];   // 64 KB double buffer

    const int blk = blockIdx.x;
    const int b = blk & 15;         // batch: same-b blocks share XCD (blk%8 const)
    const int w = blk >> 4;         // row-group 0..7
    const int tid = threadIdx.x;
    const int wave = tid >> 6;
    const int lane = tid & 63;
    const float* Pb = P + (size_t)b * T_LEN * 256;

    if (wave == 1) {
        // ---------------- producer ----------------
        // one row = 256 f32 = 64 lanes x float4
        {
            const float* src = Pb;
            float* dst = lbuf[0];
            #pragma unroll 4
            for (int rr = 0; rr < CHR; ++rr) {
                float4 v = *(const float4*)&src[(size_t)rr * 256 + lane * 4];
                *(float4*)&dst[rr * 256 + lane * 4] = v;
            }
        }
        __syncthreads();                       // chunk 0 ready
        for (int ch = 0; ch < NCH; ++ch) {
            if (ch + 1 < NCH) {
                const float* src = Pb + (size_t)(ch + 1) * CHR * 256;
                float* dst = lbuf[(ch + 1) & 1];
                #pragma unroll 4
                for (int rr = 0; rr < CHR; ++rr) {
                    float4 v = *(const float4*)&src[(size_t)rr * 256 + lane * 4];
                    *(float4*)&dst[rr * 256 + lane * 4] = v;
                }
            }
            __syncthreads();                   // flip buffers
        }
        return;
    }

    // ---------------- consumer (wave 0) ----------------
    const int c = (lane & 3) | ((lane >> 1) & 4);        // col chunk (lane bits 0,1,3)
    const int r = ((lane >> 2) & 1) | ((lane >> 3) & 6); // row-in-group (bits 2,4,5)
    const int i = w * 8 + r;        // state row 0..63
    const int kc = c * 8;           // col base

    const float da = d_alpha[i];
    const float ba = b_alpha[i];

    float s[8];
    #pragma unroll
    for (int j = 0; j < 8; j++) s[j] = 0.f;

    // two register sets: 1-step lookahead out of LDS
    float4 kaA, kbA, qaA, qbA; float vvA, aaA;
    float4 kaB, kbB, qaB, qbB; float vvB, aaB;

#define READL(rr, X) do {                                 \
        const float* rp_ = &bufp[(rr) * 256];             \
        ka##X = *(const float4*)&rp_[kc];                 \
        kb##X = *(const float4*)&rp_[kc + 4];             \
        qa##X = *(const float4*)&rp_[128 + kc];           \
        qb##X = *(const float4*)&rp_[128 + kc + 4];       \
        vv##X = rp_[64 + i];                              \
        aa##X = rp_[192 + i];                             \
    } while (0)

#define COMPUTE(t, X) do {                                                   \
        float rpa_ = s[0]*ka##X.x + s[1]*ka##X.y + s[2]*ka##X.z + s[3]*ka##X.w; \
        float rpb_ = s[4]*kb##X.x + s[5]*kb##X.y + s[6]*kb##X.z + s[7]*kb##X.w; \
        float rp_ = reduce8(rpa_ + rpb_);                                    \
        const float alpha_ = 1.f / (1.f + __expf(-(aa##X + da * rp_ + ba))); \
        const float cvk_ = (1.f - alpha_) * vv##X;                           \
        s[0] = alpha_ * s[0] + cvk_ * ka##X.x;                               \
        s[1] = alpha_ * s[1] + cvk_ * ka##X.y;                               \
        s[2] = alpha_ * s[2] + cvk_ * ka##X.z;                               \
        s[3] = alpha_ * s[3] + cvk_ * ka##X.w;                               \
        s[4] = alpha_ * s[4] + cvk_ * kb##X.x;                               \
        s[5] = alpha_ * s[5] + cvk_ * kb##X.y;                               \
        s[6] = alpha_ * s[6] + cvk_ * kb##X.z;                               \
        s[7] = alpha_ * s[7] + cvk_ * kb##X.w;                               \
        float opa_ = s[0]*qa##X.x + s[1]*qa##X.y + s[2]*qa##X.z + s[3]*qa##X.w; \
        float opb_ = s[4]*qb##X.x + s[5]*qb##X.y + s[6]*qb##X.z + s[7]*qb##X.w; \
        float op_ = reduce8(opa_ + opb_);                                    \
        const float sig_ = 1.f / (1.f + __expf(-op_));                       \
        const float o_ = op_ * op_ * sig_;                                   \
        if (c == 0)                                                          \
            cell[(size_t)(b * T_LEN + (t)) * NS + i] = __float2bfloat16(o_); \
    } while (0)

    __syncthreads();                           // chunk 0 ready
    for (int ch = 0; ch < NCH; ++ch) {
        const float* bufp = lbuf[ch & 1];
        const int t0 = ch * CHR;
        READL(0, A);
        #pragma unroll
        for (int rr = 0; rr < CHR - 2; rr += 2) {
            READL(rr + 1, B);
            COMPUTE(t0 + rr, A);
            READL(rr + 2, A);
            COMPUTE(t0 + rr + 1, B);
        }
        READL(CHR - 1, B);
        COMPUTE(t0 + CHR - 2, A);
        COMPUTE(t0 + CHR - 1, B);
        __syncthreads();                       // allow producer to overwrite this buffer
    }

#undef COMPUTE
#undef READL

    // final state
    float4 s0 = make_float4(s[0], s[1], s[2], s[3]);
    float4 s1 = make_float4(s[4], s[5], s[6], s[7]);
    *(float4*)&Sout[(size_t)b * 4096 + i * 64 + kc]     = s0;
    *(float4*)&Sout[(size_t)b * 4096 + i * 64 + kc + 4] = s1;
}

extern "C" void kernel_launch(void* const* d_in, const int* in_sizes, int n_in,
                              void* d_out, int out_size, void* d_ws, size_t ws_size,
                              hipStream_t stream) {
    const float* x     = (const float*)d_in[0];   // [32768, 1024] f32
    const float* W_in  = (const float*)d_in[1];   // [1024, 1024]
    const float* W_k   = (const float*)d_in[2];   // [64, 1024]
    const float* W_v   = (const float*)d_in[3];
    const float* W_q   = (const float*)d_in[4];
    const float* W_a   = (const float*)d_in[5];
    const float* d_alpha = (const float*)d_in[6]; // [64]
    const float* b_alpha = (const float*)d_in[7]; // [64]
    const float* W_out = (const float*)d_in[8];   // [1024, 64]

    char* ws = (char*)d_ws;
    u16*   xp     = (u16*)ws;                               // [0, 64MB)  bf16 32768x1024
    float* P      = (float*)(ws + (size_t)67108864);        // [64MB, 96MB) f32 32768x256
    u16*   Win16  = (u16*)(ws + (size_t)100663296);         // 2MB
    u16*   Wc16   = (u16*)(ws + (size_t)102760448);         // 512KB
    u16*   Wout16 = (u16*)(ws + (size_t)103284736);         // 128KB
    __hip_bfloat16* cell = (__hip_bfloat16*)ws;             // overlay [0,4MB): xp dead after P-proj

    float* out  = (float*)d_out;                  // [32768,1024] f32
    float* Sout = out + (size_t)32768 * 1024;     // [16,64,64] f32

    convert_w<<<dim3(5376), dim3(256), 0, stream>>>(W_in, W_k, W_v, W_q, W_a, W_out,
                                                    Win16, Wc16, Wout16);
    // xp = silu(x @ W_in^T), bf16
    gemm_bt<1, 1><<<dim3(256, 8), dim3(256), 0, stream>>>((const void*)x, Win16, (void*)xp,
                                                          32768, 1024, 1024);
    // P = xp @ Wc^T  (k|v|q|ax), f32
    gemm_bt<0, 0><<<dim3(256, 2), dim3(256), 0, stream>>>((const void*)xp, Wc16, (void*)P,
                                                          32768, 256, 1024);
    // producer-consumer sequential gated scan -> cell (bf16), Sout (f32)
    scan_kernel<<<dim3(128), dim3(128), 0, stream>>>(P, d_alpha, b_alpha, cell, Sout);
    // out = cell @ W_out^T, f32
    gemm_bt<0, 0><<<dim3(256, 8), dim3(256), 0, stream>>>((const void*)cell, Wout16, (void*)out,
                                                          32768, 1024, 64);
}